// Round 2
// baseline (504.279 us; speedup 1.0000x reference)
//
#include <hip/hip_runtime.h>

typedef unsigned short ushort_t;
typedef __bf16 bf16x8 __attribute__((ext_vector_type(8)));
typedef float f32x4 __attribute__((ext_vector_type(4)));

#define T_DIM 2048
#define B_DIM 2
#define E_DIM 1024
#define H_DIM 8
#define R_DIM 2
#define D_DIM 128
#define C_DIM 64
#define M_WIN 96
#define SCALING 0.08838834764831845f   // D^-0.5
#define LN2F 0.69314718055994530942f

__device__ __forceinline__ float bfu(unsigned u) {
  union { unsigned i; float f; } x; x.i = u << 16; return x.f;
}
__device__ __forceinline__ unsigned f2bf(float f) {
  union { float f; unsigned i; } x; x.f = f;
  unsigned r = x.i + 0x7fffu + ((x.i >> 16) & 1u);
  return r >> 16;
}

// ---------------------------------------------------------------------------
// fp32 SGEMM: C[M,N] = A[M,K] @ B[K,N] + bias.  Pure fp32 (hash path needs
// numpy-matching precision; bf16 MFMA noise would flip hash argmax ties).
// 256 thr = 16x16, 64x64 tile, 4x4 per thread, K-step 16.
// ---------------------------------------------------------------------------
__global__ __launch_bounds__(256) void sgemm_kernel(
    const float* __restrict__ A, const float* __restrict__ Bw,
    const float* __restrict__ bias, float* __restrict__ C,
    int Mm, int Nn, int Kk)
{
  __shared__ float As[16 * 68];   // [k][m], padded (write bank conflicts)
  __shared__ float Bs[16 * 64];   // [k][n]
  const int tid = threadIdx.x;
  const int tx = tid & 15, ty = tid >> 4;
  const int m0 = blockIdx.y * 64, n0 = blockIdx.x * 64;
  float acc[4][4] = {};

  const int ka = tid & 15, ma = tid >> 4;
  const int nb = tid & 63, kb = tid >> 6;

  for (int k0 = 0; k0 < Kk; k0 += 16) {
    __syncthreads();
#pragma unroll
    for (int pp = 0; pp < 4; ++pp) {
      As[ka * 68 + ma + pp * 16] = A[(size_t)(m0 + ma + pp * 16) * Kk + k0 + ka];
      Bs[(kb + pp * 4) * 64 + nb] = Bw[(size_t)(k0 + kb + pp * 4) * Nn + n0 + nb];
    }
    __syncthreads();
#pragma unroll
    for (int k = 0; k < 16; ++k) {
      float4 av = *(const float4*)&As[k * 68 + ty * 4];
      float4 bv = *(const float4*)&Bs[k * 64 + tx * 4];
      const float aa[4] = {av.x, av.y, av.z, av.w};
      const float bb[4] = {bv.x, bv.y, bv.z, bv.w};
#pragma unroll
      for (int i = 0; i < 4; ++i)
#pragma unroll
        for (int j = 0; j < 4; ++j) acc[i][j] += aa[i] * bb[j];
    }
  }
  float4 bv4 = *(const float4*)&bias[n0 + tx * 4];
  const float bb[4] = {bv4.x, bv4.y, bv4.z, bv4.w};
#pragma unroll
  for (int i = 0; i < 4; ++i) {
    float4 o;
    o.x = acc[i][0] + bb[0]; o.y = acc[i][1] + bb[1];
    o.z = acc[i][2] + bb[2]; o.w = acc[i][3] + bb[3];
    *(float4*)&C[(size_t)(m0 + ty * 4 + i) * Nn + n0 + tx * 4] = o;
  }
}

// ---------------------------------------------------------------------------
// bf16-MFMA GEMM for smooth paths (vf, final Wo): fp32 in, fp32 out.
// Inputs converted fp32->bf16 during LDS staging. Tile 64x64, K-step 32.
// ---------------------------------------------------------------------------
__global__ __launch_bounds__(256) void gemm_bf16_kernel(
    const float* __restrict__ A, const float* __restrict__ Bw,
    const float* __restrict__ bias, float* __restrict__ C,
    int Mm, int Nn, int Kk)
{
  __shared__ ushort_t As[64 * 40];
  __shared__ ushort_t Bs[64 * 40];
  const int tid = threadIdx.x;
  const int m0 = blockIdx.y * 64, n0 = blockIdx.x * 64;
  const int w = tid >> 6, lane = tid & 63;
  const int wm = (w >> 1) * 32, wn = (w & 1) * 32;
  const int lm = lane & 15, quad = lane >> 4;

  f32x4 acc[2][2] = {};

  const int arow = tid >> 2, acol = (tid & 3) * 8;
  const int brow = tid >> 3, bcol = (tid & 7) * 8;
  const float* aptr = A + (size_t)(m0 + arow) * Kk + acol;
  const float* bptr = Bw + (size_t)brow * Nn + n0 + bcol;

  for (int k0 = 0; k0 < Kk; k0 += 32) {
    float4 a0 = *(const float4*)(aptr + k0);
    float4 a1 = *(const float4*)(aptr + k0 + 4);
    float4 b0 = *(const float4*)(bptr + (size_t)k0 * Nn);
    float4 b1 = *(const float4*)(bptr + (size_t)k0 * Nn + 4);
    __syncthreads();
    uint4 ap;
    ap.x = f2bf(a0.x) | (f2bf(a0.y) << 16);
    ap.y = f2bf(a0.z) | (f2bf(a0.w) << 16);
    ap.z = f2bf(a1.x) | (f2bf(a1.y) << 16);
    ap.w = f2bf(a1.z) | (f2bf(a1.w) << 16);
    *(uint4*)&As[arow * 40 + acol] = ap;
    Bs[(bcol + 0) * 40 + brow] = (ushort_t)f2bf(b0.x);
    Bs[(bcol + 1) * 40 + brow] = (ushort_t)f2bf(b0.y);
    Bs[(bcol + 2) * 40 + brow] = (ushort_t)f2bf(b0.z);
    Bs[(bcol + 3) * 40 + brow] = (ushort_t)f2bf(b0.w);
    Bs[(bcol + 4) * 40 + brow] = (ushort_t)f2bf(b1.x);
    Bs[(bcol + 5) * 40 + brow] = (ushort_t)f2bf(b1.y);
    Bs[(bcol + 6) * 40 + brow] = (ushort_t)f2bf(b1.z);
    Bs[(bcol + 7) * 40 + brow] = (ushort_t)f2bf(b1.w);
    __syncthreads();
#pragma unroll
    for (int i = 0; i < 2; ++i) {
      bf16x8 av = *(const bf16x8*)&As[(wm + i * 16 + lm) * 40 + quad * 8];
#pragma unroll
      for (int j = 0; j < 2; ++j) {
        bf16x8 bv = *(const bf16x8*)&Bs[(wn + j * 16 + lm) * 40 + quad * 8];
        acc[i][j] = __builtin_amdgcn_mfma_f32_16x16x32_bf16(av, bv, acc[i][j], 0, 0, 0);
      }
    }
  }
#pragma unroll
  for (int i = 0; i < 2; ++i)
#pragma unroll
    for (int j = 0; j < 2; ++j) {
      int col = n0 + wn + j * 16 + lm;
      float bval = bias[col];
#pragma unroll
      for (int rg = 0; rg < 4; ++rg) {
        int rowi = m0 + wm + i * 16 + quad * 4 + rg;
        C[(size_t)rowi * Nn + col] = acc[i][j][rg] + bval;
      }
    }
}

// ---------------------------------------------------------------------------
// inv_norm[row] = 1/||qf[row,:]||  (row = t*B+b, over full E=1024)
// ---------------------------------------------------------------------------
__global__ __launch_bounds__(256) void norm_kernel(const float* __restrict__ qf,
                                                   float* __restrict__ inv_nrm)
{
  int row = blockIdx.x, tid = threadIdx.x;
  const float* r = qf + (size_t)row * E_DIM;
  float4 v = *(const float4*)(r + tid * 4);
  float s = v.x * v.x + v.y * v.y + v.z * v.z + v.w * v.w;
  for (int off = 1; off < 64; off <<= 1) s += __shfl_xor(s, off);
  __shared__ float part[4];
  if ((tid & 63) == 0) part[tid >> 6] = s;
  __syncthreads();
  if (tid == 0) {
    float t = part[0] + part[1] + part[2] + part[3];
    inv_nrm[row] = 1.0f / sqrtf(t);
  }
}

// ---------------------------------------------------------------------------
// hash[b][r][h][t] = argmax over [lin0..3, -lin0..3], fp32 (matches np ref).
// Scale-invariant => shared by q and k (share_kq). Block per (t*B+b).
// ---------------------------------------------------------------------------
__global__ __launch_bounds__(64) void hash_kernel(const float* __restrict__ qf,
                                                  const float* __restrict__ hw,
                                                  int* __restrict__ hashb)
{
  int row = blockIdx.x;          // t*B + b
  int t = row >> 1, b = row & 1;
  int tid = threadIdx.x;         // r*32 + h*4 + n
  int r = tid >> 5, h = (tid >> 2) & 7, n = tid & 3;
  const float* qrow = qf + (size_t)row * E_DIM + h * D_DIM;
  const float* w = hw + (size_t)(r * H_DIM + h) * D_DIM * 4 + n;
  float acc = 0.f;
  for (int d = 0; d < D_DIM; ++d) acc += qrow[d] * w[d * 4];
  __shared__ float lin[64];
  lin[tid] = acc;
  __syncthreads();
  if (n == 0) {
    int base = tid;
    float best = lin[base]; int bi = 0;
#pragma unroll
    for (int idx = 1; idx < 8; ++idx) {
      float v = (idx < 4) ? lin[base + idx] : -lin[base + idx - 4];
      if (v > best) { best = v; bi = idx; }   // strict > : first-occurrence argmax
    }
    hashb[(size_t)((b * R_DIM + r) * H_DIM + h) * T_DIM + t] = bi;
  }
}

// ---------------------------------------------------------------------------
// Stable counting sort of T=2048 tokens by hash in [0,8) per (b,r,h).
// ---------------------------------------------------------------------------
__global__ __launch_bounds__(256) void sort_kernel(const int* __restrict__ hashb,
                                                   int* __restrict__ p, int* __restrict__ inv)
{
  int bid = blockIdx.x, tid = threadIdx.x;
  const int* hrow = hashb + (size_t)bid * T_DIM;
  __shared__ int mat[8][256];
  int cnt[8];
#pragma unroll
  for (int v = 0; v < 8; ++v) cnt[v] = 0;
  int hv[8];
#pragma unroll
  for (int j = 0; j < 8; ++j) { hv[j] = hrow[tid * 8 + j]; cnt[hv[j]]++; }
#pragma unroll
  for (int v = 0; v < 8; ++v) mat[v][tid] = cnt[v];
  __syncthreads();
  if (tid == 0) {   // serial exclusive scan, bucket-major thread-minor (stable)
    int run = 0;
    for (int v = 0; v < 8; ++v)
      for (int i = 0; i < 256; ++i) { int c = mat[v][i]; mat[v][i] = run; run += c; }
  }
  __syncthreads();
#pragma unroll
  for (int j = 0; j < 8; ++j) {
    int v = hv[j];
    int pos = mat[v][tid];      // thread-private slot, no race
    mat[v][tid] = pos + 1;
    p[(size_t)bid * T_DIM + pos] = tid * 8 + j;
    inv[(size_t)bid * T_DIM + tid * 8 + j] = pos;
  }
}

// ---------------------------------------------------------------------------
// Chunked LSH attention. One block per (c,h,b*2+r). 256 threads.
// dup term: -ln2 iff key co-occurs in the other round's window.
// ---------------------------------------------------------------------------
__global__ __launch_bounds__(256) void attn_kernel(
    const float* __restrict__ qf, const float* __restrict__ vf,
    const float* __restrict__ inv_nrm, const int* __restrict__ hashb,
    const int* __restrict__ p, const int* __restrict__ inv,
    float* __restrict__ o_out, float* __restrict__ z_out)
{
  const int c = blockIdx.x, h = blockIdx.y, bz = blockIdx.z;
  const int b = bz >> 1, r = bz & 1;
  const int brh = (b * R_DIM + r) * H_DIM + h;
  const int brh_o = (b * R_DIM + (r ^ 1)) * H_DIM + h;
  const int tid = threadIdx.x;

  __shared__ ushort_t skv[M_WIN * D_DIM];   // k, then reused for v (bf16)
  __shared__ float attn_s[32 * M_WIN];
  __shared__ int sq_id[32], sk_id[M_WIN], sq_h[32], sk_h[M_WIN], cq_o[32], ck_o[M_WIN];
  __shared__ float s_invn[M_WIN];

  if (tid < M_WIN) {
    int m = tid;
    int chunk = (c + (m >> 5) + 63) & 63;          // c-1, c, c+1 (wrap)
    int pos = chunk * 32 + (m & 31);
    int t = p[(size_t)brh * T_DIM + pos];
    sk_id[m] = t;
    sk_h[m] = hashb[(size_t)brh * T_DIM + t];
    ck_o[m] = inv[(size_t)brh_o * T_DIM + t] >> 5;
    s_invn[m] = inv_nrm[t * B_DIM + b];
    if (m < 32) {
      int tq = p[(size_t)brh * T_DIM + c * 32 + m];
      sq_id[m] = tq;
      sq_h[m] = hashb[(size_t)brh * T_DIM + tq];
      cq_o[m] = inv[(size_t)brh_o * T_DIM + tq] >> 5;
    }
  }
  __syncthreads();

  // stage k (normalized qf) as bf16
  for (int idx = tid; idx < M_WIN * 32; idx += 256) {
    int m = idx >> 5, seg = idx & 31;
    int t = sk_id[m];
    float inrm = s_invn[m];
    float4 v = *(const float4*)(qf + (size_t)(t * B_DIM + b) * E_DIM + h * D_DIM + seg * 4);
    uint2 o2;
    o2.x = f2bf(v.x * inrm) | (f2bf(v.y * inrm) << 16);
    o2.y = f2bf(v.z * inrm) | (f2bf(v.w * inrm) << 16);
    *(uint2*)&skv[m * D_DIM + seg * 4] = o2;
  }
  __syncthreads();

  const int l = tid >> 3, g = tid & 7;
  const int tq = sq_id[l];
  float qr[16];
  {
    const float* qrow = qf + (size_t)(tq * B_DIM + b) * E_DIM + h * D_DIM + g * 16;
#pragma unroll
    for (int j = 0; j < 16; j += 4) {
      float4 v = *(const float4*)(qrow + j);
      qr[j] = v.x * SCALING; qr[j + 1] = v.y * SCALING;
      qr[j + 2] = v.z * SCALING; qr[j + 3] = v.w * SCALING;
    }
  }
  const int myqh = sq_h[l];
  const int mycq = cq_o[l];

  float smy[12];
  for (int m = 0; m < M_WIN; ++m) {
    const ushort_t* krow = &skv[m * D_DIM + g * 16];
    uint4 ka = *(const uint4*)krow;
    uint4 kb = *(const uint4*)(krow + 8);
    float acc = 0.f;
    acc += qr[0] * bfu(ka.x & 0xffffu) + qr[1] * bfu(ka.x >> 16);
    acc += qr[2] * bfu(ka.y & 0xffffu) + qr[3] * bfu(ka.y >> 16);
    acc += qr[4] * bfu(ka.z & 0xffffu) + qr[5] * bfu(ka.z >> 16);
    acc += qr[6] * bfu(ka.w & 0xffffu) + qr[7] * bfu(ka.w >> 16);
    acc += qr[8] * bfu(kb.x & 0xffffu) + qr[9] * bfu(kb.x >> 16);
    acc += qr[10] * bfu(kb.y & 0xffffu) + qr[11] * bfu(kb.y >> 16);
    acc += qr[12] * bfu(kb.z & 0xffffu) + qr[13] * bfu(kb.z >> 16);
    acc += qr[14] * bfu(kb.w & 0xffffu) + qr[15] * bfu(kb.w >> 16);
    acc += __shfl_xor(acc, 1);
    acc += __shfl_xor(acc, 2);
    acc += __shfl_xor(acc, 4);
    float sc = acc;
    if (sk_h[m] != myqh) sc -= 1.0e16f;   // mask_different_hashes
    if (sk_id[m] == tq)  sc -= 1.0e8f;    // mask_current
    int dc = (ck_o[m] - mycq) & 63;
    if (dc <= 1 || dc == 63) sc -= LN2F;  // -log(dup), dup = 1 + other-round co-occurrence
    if ((m & 7) == g) smy[m >> 3] = sc;
  }

  float mx = smy[0];
#pragma unroll
  for (int j = 1; j < 12; ++j) mx = fmaxf(mx, smy[j]);
  mx = fmaxf(mx, __shfl_xor(mx, 1));
  mx = fmaxf(mx, __shfl_xor(mx, 2));
  mx = fmaxf(mx, __shfl_xor(mx, 4));
  float sum = 0.f, ey[12];
#pragma unroll
  for (int j = 0; j < 12; ++j) { ey[j] = expf(smy[j] - mx); sum += ey[j]; }
  sum += __shfl_xor(sum, 1);
  sum += __shfl_xor(sum, 2);
  sum += __shfl_xor(sum, 4);
  float inv_s = 1.0f / sum;
#pragma unroll
  for (int j = 0; j < 12; ++j) attn_s[l * M_WIN + g + 8 * j] = ey[j] * inv_s;
  if (g == 0) z_out[(size_t)brh * T_DIM + tq] = mx + logf(sum);

  __syncthreads();   // all skv reads + attn_s writes done

  // stage v (bf16), reuse skv
  for (int idx = tid; idx < M_WIN * 32; idx += 256) {
    int m = idx >> 5, seg = idx & 31;
    int t = sk_id[m];
    float4 v = *(const float4*)(vf + (size_t)(t * B_DIM + b) * E_DIM + h * D_DIM + seg * 4);
    uint2 o2;
    o2.x = f2bf(v.x) | (f2bf(v.y) << 16);
    o2.y = f2bf(v.z) | (f2bf(v.w) << 16);
    *(uint2*)&skv[m * D_DIM + seg * 4] = o2;
  }
  __syncthreads();

  const int ls = tid >> 7;
  const int d = tid & 127;
  float oacc[16];
#pragma unroll
  for (int j = 0; j < 16; ++j) oacc[j] = 0.f;
  for (int m = 0; m < M_WIN; ++m) {
    float vmd = bfu((unsigned)skv[m * D_DIM + d]);
#pragma unroll
    for (int j = 0; j < 16; ++j)
      oacc[j] += attn_s[(ls * 16 + j) * M_WIN + m] * vmd;
  }
#pragma unroll
  for (int j = 0; j < 16; ++j) {
    int tqo = sq_id[ls * 16 + j];
    o_out[((size_t)brh * T_DIM + tqo) * D_DIM + d] = oacc[j];
  }
}

// ---------------------------------------------------------------------------
// Combine rounds: w = softmax(z over R), ctx[t,b,h*D+d] = sum_r w_r*o_r (fp32)
// ---------------------------------------------------------------------------
__global__ __launch_bounds__(256) void combine_kernel(const float* __restrict__ o_buf,
                                                      const float* __restrict__ z_buf,
                                                      float* __restrict__ ctx)
{
  int gid = blockIdx.x * 256 + threadIdx.x;
  int d = gid & 127;
  int t = (gid >> 7) & (T_DIM - 1);
  int h = (gid >> 18) & 7;
  int b = gid >> 21;
  int brh0 = (b * R_DIM + 0) * H_DIM + h;
  int brh1 = brh0 + H_DIM;
  float z0 = z_buf[(size_t)brh0 * T_DIM + t], z1 = z_buf[(size_t)brh1 * T_DIM + t];
  float mz = fmaxf(z0, z1);
  float e0 = expf(z0 - mz), e1 = expf(z1 - mz);
  float o0 = o_buf[((size_t)brh0 * T_DIM + t) * D_DIM + d];
  float o1 = o_buf[((size_t)brh1 * T_DIM + t) * D_DIM + d];
  float val = (e0 * o0 + e1 * o1) / (e0 + e1);
  ctx[((size_t)t * B_DIM + b) * E_DIM + h * D_DIM + d] = val;
}

// ---------------------------------------------------------------------------
extern "C" void kernel_launch(void* const* d_in, const int* in_sizes, int n_in,
                              void* d_out, int out_size, void* d_ws, size_t ws_size,
                              hipStream_t stream)
{
  const float* query = (const float*)d_in[0];
  // d_in[1] = key, unused (share_kq)
  const float* value = (const float*)d_in[2];
  const float* Wq = (const float*)d_in[3];
  const float* bq = (const float*)d_in[4];
  const float* Wv = (const float*)d_in[5];
  const float* bv = (const float*)d_in[6];
  const float* Wo = (const float*)d_in[7];
  const float* bo = (const float*)d_in[8];
  const float* hw = (const float*)d_in[9];

  float* ws = (float*)d_ws;
  float* qf      = ws;                         // 4,194,304 f32
  float* vf      = qf + 4194304;               // 4,194,304 f32
  float* ctx     = vf + 4194304;               // 4,194,304 f32
  float* obuf    = ctx + 4194304;              // 8,388,608 f32
  float* zbuf    = obuf + 8388608;             // 65,536 f32
  float* inv_nrm = zbuf + 65536;               // 4,096 f32
  int*   hashb   = (int*)(inv_nrm + 4096);     // 65,536 i32
  int*   pperm   = hashb + 65536;              // 65,536 i32
  int*   pinv    = pperm + 65536;              // 65,536 i32

  dim3 gg(16, 64);
  sgemm_kernel<<<gg, 256, 0, stream>>>(query, Wq, bq, qf, 4096, 1024, 1024);
  gemm_bf16_kernel<<<gg, 256, 0, stream>>>(value, Wv, bv, vf, 4096, 1024, 1024);
  norm_kernel<<<4096, 256, 0, stream>>>(qf, inv_nrm);
  hash_kernel<<<4096, 64, 0, stream>>>(qf, hw, hashb);
  sort_kernel<<<32, 256, 0, stream>>>(hashb, pperm, pinv);
  attn_kernel<<<dim3(64, 8, 4), 256, 0, stream>>>(qf, vf, inv_nrm, hashb, pperm, pinv, obuf, zbuf);
  combine_kernel<<<16384, 256, 0, stream>>>(obuf, zbuf, ctx);
  gemm_bf16_kernel<<<gg, 256, 0, stream>>>(ctx, Wo, bo, (float*)d_out, 4096, 1024, 1024);
}

// Round 3
// 283.106 us; speedup vs baseline: 1.7812x; 1.7812x over previous
//
#include <hip/hip_runtime.h>

typedef unsigned short ushort_t;
typedef __bf16 bf16x8 __attribute__((ext_vector_type(8)));
typedef float f32x4 __attribute__((ext_vector_type(4)));

#define T_DIM 2048
#define B_DIM 2
#define E_DIM 1024
#define H_DIM 8
#define R_DIM 2
#define D_DIM 128
#define M_WIN 96
#define SCALING 0.08838834764831845f   // D^-0.5
#define LN2F 0.69314718055994530942f

__device__ __forceinline__ float bfu(unsigned u) {
  union { unsigned i; float f; } x; x.i = u << 16; return x.f;
}
__device__ __forceinline__ unsigned f2bf(float f) {
  union { float f; unsigned i; } x; x.f = f;
  unsigned r = x.i + 0x7fffu + ((x.i >> 16) & 1u);
  return r >> 16;
}
__device__ __forceinline__ void gl_lds16(const void* g, void* l) {
  __builtin_amdgcn_global_load_lds(
      (const __attribute__((address_space(1))) unsigned int*)g,
      (__attribute__((address_space(3))) unsigned int*)l, 16, 0, 0);
}

// ---------------------------------------------------------------------------
// pack: fp32 -> bf16 hi (+ optional lo residual). 4 elems/thread, exact grids.
// ---------------------------------------------------------------------------
__global__ __launch_bounds__(256) void pack2_kernel(const float* __restrict__ in,
                                                    ushort_t* __restrict__ hi,
                                                    ushort_t* __restrict__ lo)
{
  int i = (blockIdx.x * 256 + threadIdx.x) * 4;
  float4 v = *(const float4*)&in[i];
  unsigned h0 = f2bf(v.x), h1 = f2bf(v.y), h2 = f2bf(v.z), h3 = f2bf(v.w);
  uint2 oh; oh.x = h0 | (h1 << 16); oh.y = h2 | (h3 << 16);
  *(uint2*)&hi[i] = oh;
  unsigned l0 = f2bf(v.x - bfu(h0)), l1 = f2bf(v.y - bfu(h1));
  unsigned l2 = f2bf(v.z - bfu(h2)), l3 = f2bf(v.w - bfu(h3));
  uint2 ol; ol.x = l0 | (l1 << 16); ol.y = l2 | (l3 << 16);
  *(uint2*)&lo[i] = ol;
}

__global__ __launch_bounds__(256) void pack1_kernel(const float* __restrict__ in,
                                                    ushort_t* __restrict__ hi)
{
  int i = (blockIdx.x * 256 + threadIdx.x) * 4;
  float4 v = *(const float4*)&in[i];
  uint2 oh;
  oh.x = f2bf(v.x) | (f2bf(v.y) << 16);
  oh.y = f2bf(v.z) | (f2bf(v.w) << 16);
  *(uint2*)&hi[i] = oh;
}

// ---------------------------------------------------------------------------
// packT: W[K][N] fp32 -> WT[N][K] bf16 hi (+ optional lo). 64x64 LDS tiles.
// ---------------------------------------------------------------------------
__global__ __launch_bounds__(256) void packT_kernel(const float* __restrict__ in,
                                                    ushort_t* __restrict__ hi,
                                                    ushort_t* __restrict__ lo,
                                                    int Kk, int Nn)
{
  __shared__ float tile[64][65];
  const int tid = threadIdx.x;
  const int k0 = blockIdx.y * 64, n0 = blockIdx.x * 64;
  const int tr = tid >> 4, tc4 = (tid & 15) * 4;
#pragma unroll
  for (int rr = 0; rr < 64; rr += 16)
    *(float4*)&tile[tr + rr][tc4] = *(const float4*)&in[(size_t)(k0 + tr + rr) * Nn + n0 + tc4];
  __syncthreads();
#pragma unroll
  for (int rr = 0; rr < 64; rr += 16) {
    int n = n0 + tr + rr;
    float v0 = tile[tc4 + 0][tr + rr];
    float v1 = tile[tc4 + 1][tr + rr];
    float v2 = tile[tc4 + 2][tr + rr];
    float v3 = tile[tc4 + 3][tr + rr];
    unsigned h0 = f2bf(v0), h1 = f2bf(v1), h2 = f2bf(v2), h3 = f2bf(v3);
    uint2 oh; oh.x = h0 | (h1 << 16); oh.y = h2 | (h3 << 16);
    *(uint2*)&hi[(size_t)n * Kk + k0 + tc4] = oh;
    if (lo) {
      uint2 ol;
      ol.x = f2bf(v0 - bfu(h0)) | (f2bf(v1 - bfu(h1)) << 16);
      ol.y = f2bf(v2 - bfu(h2)) | (f2bf(v3 - bfu(h3)) << 16);
      *(uint2*)&lo[(size_t)n * Kk + k0 + tc4] = ol;
    }
  }
}

// ---------------------------------------------------------------------------
// MFMA GEMM, tile 128(M)x64(N), BK=32, global_load_lds(16B) staging.
// A[M][K] bf16 (hi + optional lo), BT[N][K] bf16 (hi + optional lo).
// 3-term mode: C = Ah*Bh + Al*Bh + Ah*Bl (fp32-class accuracy).
// C fp32 = A@B + bias. Grid (N/64, M/128), 256 threads (2x2 waves).
// ---------------------------------------------------------------------------
__global__ __launch_bounds__(256) void gemm_mfma(
    const ushort_t* __restrict__ Ah, const ushort_t* __restrict__ Al,
    const ushort_t* __restrict__ Bh, const ushort_t* __restrict__ Bl,
    const float* __restrict__ bias, float* __restrict__ C,
    int Mm, int Nn, int Kk)
{
  __shared__ ushort_t As[128 * 32];
  __shared__ ushort_t Bs[64 * 32];
  __shared__ ushort_t As2[128 * 32];
  __shared__ ushort_t Bs2[64 * 32];
  const int tid = threadIdx.x;
  const int w = tid >> 6, lane = tid & 63;
  const int lm = lane & 15, quad = lane >> 4;
  const int wr = w >> 1, wc = w & 1;
  const int m0 = blockIdx.y * 128, n0 = blockIdx.x * 64;
  const bool three = (Al != nullptr);

  f32x4 acc[4][2] = {};

  for (int k0 = 0; k0 < Kk; k0 += 32) {
    __syncthreads();
    // A tile: 512 chunks of 16B; 2 calls/wave
#pragma unroll
    for (int j = 0; j < 2; ++j) {
      int g = j * 256 + w * 64 + lane;
      gl_lds16(Ah + (size_t)(m0 + (g >> 2)) * Kk + k0 + (g & 3) * 8,
               &As[(size_t)(j * 256 + w * 64) * 8]);
    }
    // B tile: 256 chunks; 1 call/wave
    {
      int g = w * 64 + lane;
      gl_lds16(Bh + (size_t)(n0 + (g >> 2)) * Kk + k0 + (g & 3) * 8,
               &Bs[(size_t)(w * 64) * 8]);
    }
    if (three) {
#pragma unroll
      for (int j = 0; j < 2; ++j) {
        int g = j * 256 + w * 64 + lane;
        gl_lds16(Al + (size_t)(m0 + (g >> 2)) * Kk + k0 + (g & 3) * 8,
                 &As2[(size_t)(j * 256 + w * 64) * 8]);
      }
      int g = w * 64 + lane;
      gl_lds16(Bl + (size_t)(n0 + (g >> 2)) * Kk + k0 + (g & 3) * 8,
               &Bs2[(size_t)(w * 64) * 8]);
    }
    __syncthreads();

    bf16x8 av[4], bv[2];
#pragma unroll
    for (int i = 0; i < 4; ++i) av[i] = *(const bf16x8*)&As[(wr * 64 + i * 16 + lm) * 32 + quad * 8];
#pragma unroll
    for (int j = 0; j < 2; ++j) bv[j] = *(const bf16x8*)&Bs[(wc * 32 + j * 16 + lm) * 32 + quad * 8];
    if (three) {
      bf16x8 av2[4], bv2[2];
#pragma unroll
      for (int i = 0; i < 4; ++i) av2[i] = *(const bf16x8*)&As2[(wr * 64 + i * 16 + lm) * 32 + quad * 8];
#pragma unroll
      for (int j = 0; j < 2; ++j) bv2[j] = *(const bf16x8*)&Bs2[(wc * 32 + j * 16 + lm) * 32 + quad * 8];
#pragma unroll
      for (int i = 0; i < 4; ++i)
#pragma unroll
        for (int j = 0; j < 2; ++j) {
          acc[i][j] = __builtin_amdgcn_mfma_f32_16x16x32_bf16(av[i], bv[j], acc[i][j], 0, 0, 0);
          acc[i][j] = __builtin_amdgcn_mfma_f32_16x16x32_bf16(av2[i], bv[j], acc[i][j], 0, 0, 0);
          acc[i][j] = __builtin_amdgcn_mfma_f32_16x16x32_bf16(av[i], bv2[j], acc[i][j], 0, 0, 0);
        }
    } else {
#pragma unroll
      for (int i = 0; i < 4; ++i)
#pragma unroll
        for (int j = 0; j < 2; ++j)
          acc[i][j] = __builtin_amdgcn_mfma_f32_16x16x32_bf16(av[i], bv[j], acc[i][j], 0, 0, 0);
    }
  }

#pragma unroll
  for (int j = 0; j < 2; ++j) {
    int col = n0 + wc * 32 + j * 16 + lm;
    float bj = bias[col];
#pragma unroll
    for (int i = 0; i < 4; ++i)
#pragma unroll
      for (int rg = 0; rg < 4; ++rg)
        C[(size_t)(m0 + wr * 64 + i * 16 + quad * 4 + rg) * Nn + col] = acc[i][j][rg] + bj;
  }
}

// ---------------------------------------------------------------------------
// inv_norm[row] = 1/||qf[row,:]||
// ---------------------------------------------------------------------------
__global__ __launch_bounds__(256) void norm_kernel(const float* __restrict__ qf,
                                                   float* __restrict__ inv_nrm)
{
  int row = blockIdx.x, tid = threadIdx.x;
  const float* r = qf + (size_t)row * E_DIM;
  float4 v = *(const float4*)(r + tid * 4);
  float s = v.x * v.x + v.y * v.y + v.z * v.z + v.w * v.w;
  for (int off = 1; off < 64; off <<= 1) s += __shfl_xor(s, off);
  __shared__ float part[4];
  if ((tid & 63) == 0) part[tid >> 6] = s;
  __syncthreads();
  if (tid == 0) {
    float t = part[0] + part[1] + part[2] + part[3];
    inv_nrm[row] = 1.0f / sqrtf(t);
  }
}

// ---------------------------------------------------------------------------
// hash: block = 16 rows x 16 (r,h) threads; hash_w cached in LDS (padded).
// argmax over [lin0..3, -lin0..3], first occurrence (strict >).
// ---------------------------------------------------------------------------
__global__ __launch_bounds__(256) void hash_kernel(const float* __restrict__ qf,
                                                   const float* __restrict__ hw,
                                                   int* __restrict__ hashb)
{
  __shared__ float wlds[16 * 516];   // [rh][d*4+n], stride 516 (bank spread)
  const int tid = threadIdx.x;
  for (int i = tid; i < 8192; i += 256) wlds[(i >> 9) * 516 + (i & 511)] = hw[i];
  __syncthreads();
  const int rloc = tid >> 4, rh = tid & 15;
  const int r = rh >> 3, h = rh & 7;
  const int row = blockIdx.x * 16 + rloc;   // t*B + b
  const float* qrow = qf + (size_t)row * E_DIM + h * D_DIM;
  const float* wp = &wlds[rh * 516];
  float a0 = 0.f, a1 = 0.f, a2 = 0.f, a3 = 0.f;
  for (int d = 0; d < 128; d += 4) {
    float4 q4 = *(const float4*)&qrow[d];
    float4 w0 = *(const float4*)&wp[d * 4];
    float4 w1 = *(const float4*)&wp[d * 4 + 4];
    float4 w2 = *(const float4*)&wp[d * 4 + 8];
    float4 w3 = *(const float4*)&wp[d * 4 + 12];
    a0 += q4.x * w0.x + q4.y * w1.x + q4.z * w2.x + q4.w * w3.x;
    a1 += q4.x * w0.y + q4.y * w1.y + q4.z * w2.y + q4.w * w3.y;
    a2 += q4.x * w0.z + q4.y * w1.z + q4.z * w2.z + q4.w * w3.z;
    a3 += q4.x * w0.w + q4.y * w1.w + q4.z * w2.w + q4.w * w3.w;
  }
  float lin[4] = {a0, a1, a2, a3};
  float best = lin[0]; int bi = 0;
#pragma unroll
  for (int idx = 1; idx < 8; ++idx) {
    float v = (idx < 4) ? lin[idx] : -lin[idx - 4];
    if (v > best) { best = v; bi = idx; }
  }
  int t = row >> 1, b = row & 1;
  hashb[(size_t)((b * R_DIM + r) * H_DIM + h) * T_DIM + t] = bi;
}

// ---------------------------------------------------------------------------
// Stable counting sort by hash in [0,8) per (b,r,h). Parallel scan.
// ---------------------------------------------------------------------------
__global__ __launch_bounds__(256) void sort_kernel(const int* __restrict__ hashb,
                                                   int* __restrict__ p, int* __restrict__ inv)
{
  const int bid = blockIdx.x, tid = threadIdx.x;
  const int lane = tid & 63, w = tid >> 6;
  const int* hrow = hashb + (size_t)bid * T_DIM;
  __shared__ int mat[8][256];
  __shared__ int btot[8], bbase[8];
  int cnt[8];
#pragma unroll
  for (int v = 0; v < 8; ++v) cnt[v] = 0;
  int hv[8];
#pragma unroll
  for (int j = 0; j < 8; ++j) { hv[j] = hrow[tid * 8 + j]; cnt[hv[j]]++; }
#pragma unroll
  for (int v = 0; v < 8; ++v) mat[v][tid] = cnt[v];
  __syncthreads();
  for (int v = w; v < 8; v += 4) {   // wave w scans buckets w, w+4
    int4 c4 = *(const int4*)&mat[v][lane * 4];
    int s = c4.x + c4.y + c4.z + c4.w;
    int x = s;
    for (int off = 1; off < 64; off <<= 1) {
      int y = __shfl_up(x, off);
      if (lane >= off) x += y;
    }
    int excl = x - s;
    mat[v][lane * 4 + 0] = excl;
    mat[v][lane * 4 + 1] = excl + c4.x;
    mat[v][lane * 4 + 2] = excl + c4.x + c4.y;
    mat[v][lane * 4 + 3] = excl + c4.x + c4.y + c4.z;
    if (lane == 63) btot[v] = x;
  }
  __syncthreads();
  if (tid == 0) {
    int run = 0;
    for (int v = 0; v < 8; ++v) { bbase[v] = run; run += btot[v]; }
  }
  __syncthreads();
#pragma unroll
  for (int v = 0; v < 8; ++v) cnt[v] = 0;
#pragma unroll
  for (int j = 0; j < 8; ++j) {
    int v = hv[j];
    int pos = bbase[v] + mat[v][tid] + cnt[v];
    cnt[v]++;
    p[(size_t)bid * T_DIM + pos] = tid * 8 + j;
    inv[(size_t)bid * T_DIM + tid * 8 + j] = pos;
  }
}

// ---------------------------------------------------------------------------
// Chunked LSH attention, MFMA. Block per (c,h,b*2+r), 256 threads (4 waves).
// Phase1: Q[32x128],K[96x128] bf16 LDS -> S=Q@K^T via MFMA (48 mfma).
// Phase2: masks -> SS fp32; V^T staged; softmax -> P bf16; O=P@V via MFMA.
// LDS strides padded (136/104/98) for conflict-free ds_read_b128.
// ---------------------------------------------------------------------------
__global__ __launch_bounds__(256) void attn_kernel(
    const float* __restrict__ qf, const float* __restrict__ vf,
    const float* __restrict__ inv_nrm, const int* __restrict__ hashb,
    const int* __restrict__ p, const int* __restrict__ inv,
    float* __restrict__ o_out, float* __restrict__ z_out)
{
  const int c = blockIdx.x, h = blockIdx.y, bz = blockIdx.z;
  const int b = bz >> 1, r = bz & 1;
  const int brh = (b * R_DIM + r) * H_DIM + h;
  const int brh_o = (b * R_DIM + (r ^ 1)) * H_DIM + h;
  const int tid = threadIdx.x;
  const int lane = tid & 63, w = tid >> 6;
  const int lm = lane & 15, quad = lane >> 4;

  // union LDS: phase1 {Qs@0:8704, Ks@8704:34816} ; phase2 {VT@0:26624,
  // SS@26624:+12544, Ps@39168:+6656}
  __shared__ __align__(16) unsigned char smem[45824];
  ushort_t* Qs = (ushort_t*)smem;                 // [32][136]
  ushort_t* Ks = (ushort_t*)(smem + 8704);        // [96][136]
  ushort_t* VT = (ushort_t*)smem;                 // [128][104]
  float*    SS = (float*)(smem + 26624);          // [32][98]
  ushort_t* Ps = (ushort_t*)(smem + 39168);       // [32][104]
  __shared__ int sq_id[32], sq_h[32], cq_o[32];
  __shared__ int sk_id[M_WIN], sk_h[M_WIN], ck_o[M_WIN];
  __shared__ float s_invn[M_WIN];

  if (tid < M_WIN) {
    int m = tid;
    int chunk = (c + (m >> 5) + 63) & 63;          // c-1, c, c+1 (wrap)
    int pos = chunk * 32 + (m & 31);
    int t = p[(size_t)brh * T_DIM + pos];
    sk_id[m] = t;
    sk_h[m] = hashb[(size_t)brh * T_DIM + t];
    ck_o[m] = inv[(size_t)brh_o * T_DIM + t] >> 5;
    s_invn[m] = inv_nrm[t * B_DIM + b];
    if (m < 32) {
      int tq = p[(size_t)brh * T_DIM + c * 32 + m];
      sq_id[m] = tq;
      sq_h[m] = hashb[(size_t)brh * T_DIM + tq];
      cq_o[m] = inv[(size_t)brh_o * T_DIM + tq] >> 5;
    }
  }
  __syncthreads();

  // stage Q (scaled) and K (normalized) as bf16
  for (int idx = tid; idx < 1024; idx += 256) {
    int row = idx >> 5, seg = idx & 31;
    int t = sq_id[row];
    float4 v = *(const float4*)(qf + ((size_t)(t * B_DIM + b) << 10) + h * D_DIM + seg * 4);
    uint2 o2;
    o2.x = f2bf(v.x * SCALING) | (f2bf(v.y * SCALING) << 16);
    o2.y = f2bf(v.z * SCALING) | (f2bf(v.w * SCALING) << 16);
    *(uint2*)&Qs[row * 136 + seg * 4] = o2;
  }
  for (int idx = tid; idx < 3072; idx += 256) {
    int m = idx >> 5, seg = idx & 31;
    int t = sk_id[m];
    float inrm = s_invn[m];
    float4 v = *(const float4*)(qf + ((size_t)(t * B_DIM + b) << 10) + h * D_DIM + seg * 4);
    uint2 o2;
    o2.x = f2bf(v.x * inrm) | (f2bf(v.y * inrm) << 16);
    o2.y = f2bf(v.z * inrm) | (f2bf(v.w * inrm) << 16);
    *(uint2*)&Ks[m * 136 + seg * 4] = o2;
  }
  __syncthreads();

  // scores MFMA: wave w -> m-tile (w&1), n-tiles (w>>1)*3 + {0,1,2}
  const int mw = w & 1, nset = w >> 1;
  bf16x8 av[4];
#pragma unroll
  for (int kk = 0; kk < 4; ++kk)
    av[kk] = *(const bf16x8*)&Qs[(mw * 16 + lm) * 136 + kk * 32 + quad * 8];
  f32x4 sacc[3] = {};
#pragma unroll
  for (int jj = 0; jj < 3; ++jj) {
    int nt = nset * 3 + jj;
#pragma unroll
    for (int kk = 0; kk < 4; ++kk) {
      bf16x8 bv = *(const bf16x8*)&Ks[(nt * 16 + lm) * 136 + kk * 32 + quad * 8];
      sacc[jj] = __builtin_amdgcn_mfma_f32_16x16x32_bf16(av[kk], bv, sacc[jj], 0, 0, 0);
    }
  }
  __syncthreads();   // Q/K reads done; safe to overwrite union

  // epilogue: masks -> SS (C layout: row = mw*16+quad*4+rg, col = nt*16+lm)
  const int rowb = mw * 16 + quad * 4;
#pragma unroll
  for (int jj = 0; jj < 3; ++jj) {
    int col = (nset * 3 + jj) * 16 + lm;
    int kh = sk_h[col], kid = sk_id[col], kco = ck_o[col];
#pragma unroll
    for (int rg = 0; rg < 4; ++rg) {
      int row = rowb + rg;
      float sc = sacc[jj][rg];
      if (kh != sq_h[row]) sc -= 1.0e16f;   // mask_different_hashes
      if (kid == sq_id[row]) sc -= 1.0e8f;  // mask_current
      int dc = (kco - cq_o[row]) & 63;
      if (dc <= 1 || dc == 63) sc -= LN2F;  // -log(dup)
      SS[row * 98 + col] = sc;
    }
  }
  // stage V^T: VT[d][m] = V[m][d]
  for (int idx = tid; idx < 3072; idx += 256) {
    int d = idx & 127, mg = idx >> 7;   // mg in [0,24)
    unsigned vv0, vv1, vv2, vv3;
    {
      int t0 = sk_id[mg * 4 + 0], t1 = sk_id[mg * 4 + 1];
      int t2 = sk_id[mg * 4 + 2], t3 = sk_id[mg * 4 + 3];
      const size_t off = (size_t)h * D_DIM + d;
      vv0 = f2bf(vf[((size_t)(t0 * B_DIM + b) << 10) + off]);
      vv1 = f2bf(vf[((size_t)(t1 * B_DIM + b) << 10) + off]);
      vv2 = f2bf(vf[((size_t)(t2 * B_DIM + b) << 10) + off]);
      vv3 = f2bf(vf[((size_t)(t3 * B_DIM + b) << 10) + off]);
    }
    uint2 o2; o2.x = vv0 | (vv1 << 16); o2.y = vv2 | (vv3 << 16);
    *(uint2*)&VT[d * 104 + mg * 4] = o2;
  }
  __syncthreads();

  // softmax over 96 cols: 8 threads per row
  {
    const int l = tid >> 3, g = tid & 7;
    float smy[12];
#pragma unroll
    for (int j = 0; j < 12; ++j) smy[j] = SS[l * 98 + g + 8 * j];
    float mx = smy[0];
#pragma unroll
    for (int j = 1; j < 12; ++j) mx = fmaxf(mx, smy[j]);
    mx = fmaxf(mx, __shfl_xor(mx, 1));
    mx = fmaxf(mx, __shfl_xor(mx, 2));
    mx = fmaxf(mx, __shfl_xor(mx, 4));
    float sum = 0.f, ey[12];
#pragma unroll
    for (int j = 0; j < 12; ++j) { ey[j] = expf(smy[j] - mx); sum += ey[j]; }
    sum += __shfl_xor(sum, 1);
    sum += __shfl_xor(sum, 2);
    sum += __shfl_xor(sum, 4);
    float inv_s = 1.0f / sum;
#pragma unroll
    for (int j = 0; j < 12; ++j)
      Ps[l * 104 + g + 8 * j] = (ushort_t)f2bf(ey[j] * inv_s);
    if (g == 0) z_out[(size_t)brh * T_DIM + sq_id[l]] = mx + logf(sum);
  }
  __syncthreads();

  // PV MFMA: wave w -> m-tile (w&1), d-tiles (w>>1)*4 + {0..3}; K=96
  const int dset = w >> 1;
  bf16x8 pa[3];
#pragma unroll
  for (int kk = 0; kk < 3; ++kk)
    pa[kk] = *(const bf16x8*)&Ps[(mw * 16 + lm) * 104 + kk * 32 + quad * 8];
  f32x4 oacc[4] = {};
#pragma unroll
  for (int jj = 0; jj < 4; ++jj) {
    int dt = dset * 4 + jj;
#pragma unroll
    for (int kk = 0; kk < 3; ++kk) {
      bf16x8 bv = *(const bf16x8*)&VT[(dt * 16 + lm) * 104 + kk * 32 + quad * 8];
      oacc[jj] = __builtin_amdgcn_mfma_f32_16x16x32_bf16(pa[kk], bv, oacc[jj], 0, 0, 0);
    }
  }
#pragma unroll
  for (int jj = 0; jj < 4; ++jj) {
    int col = (dset * 4 + jj) * 16 + lm;
#pragma unroll
    for (int rg = 0; rg < 4; ++rg) {
      int row = rowb + rg;
      int tqo = sq_id[row];
      o_out[((size_t)brh * T_DIM + tqo) * D_DIM + col] = oacc[jj][rg];
    }
  }
}

// ---------------------------------------------------------------------------
// Combine rounds -> ctx bf16 [t*B+b][E]
// ---------------------------------------------------------------------------
__global__ __launch_bounds__(256) void combine_kernel(const float* __restrict__ o_buf,
                                                      const float* __restrict__ z_buf,
                                                      ushort_t* __restrict__ ctx)
{
  int gid = blockIdx.x * 256 + threadIdx.x;
  int d = gid & 127;
  int t = (gid >> 7) & (T_DIM - 1);
  int h = (gid >> 18) & 7;
  int b = gid >> 21;
  int brh0 = (b * R_DIM + 0) * H_DIM + h;
  int brh1 = brh0 + H_DIM;
  float z0 = z_buf[(size_t)brh0 * T_DIM + t], z1 = z_buf[(size_t)brh1 * T_DIM + t];
  float mz = fmaxf(z0, z1);
  float e0 = expf(z0 - mz), e1 = expf(z1 - mz);
  float o0 = o_buf[((size_t)brh0 * T_DIM + t) * D_DIM + d];
  float o1 = o_buf[((size_t)brh1 * T_DIM + t) * D_DIM + d];
  float val = (e0 * o0 + e1 * o1) / (e0 + e1);
  ctx[((size_t)t * B_DIM + b) * E_DIM + h * D_DIM + d] = (ushort_t)f2bf(val);
}

// ---------------------------------------------------------------------------
extern "C" void kernel_launch(void* const* d_in, const int* in_sizes, int n_in,
                              void* d_out, int out_size, void* d_ws, size_t ws_size,
                              hipStream_t stream)
{
  const float* query = (const float*)d_in[0];
  // d_in[1] = key, unused (share_kq)
  const float* value = (const float*)d_in[2];
  const float* Wq = (const float*)d_in[3];
  const float* bq = (const float*)d_in[4];
  const float* Wv = (const float*)d_in[5];
  const float* bv = (const float*)d_in[6];
  const float* Wo = (const float*)d_in[7];
  const float* bo = (const float*)d_in[8];
  const float* hw = (const float*)d_in[9];

  float* ws = (float*)d_ws;
  float* qf      = ws;                          // 16.78 MB
  float* vf      = qf + 4194304;                // 16.78 MB
  float* obuf    = vf + 4194304;                // 33.55 MB
  float* zbuf    = obuf + 8388608;
  float* inv_nrm = zbuf + 65536;
  int*   hashb   = (int*)(inv_nrm + 4096);
  int*   pperm   = hashb + 65536;
  int*   pinv    = pperm + 65536;
  ushort_t* WqTh = (ushort_t*)(pinv + 65536);
  ushort_t* WqTl = WqTh + 1048576;
  ushort_t* WvTh = WqTl + 1048576;
  ushort_t* WoTh = WvTh + 1048576;
  // overlays (lifetime-disjoint):
  ushort_t* qh  = (ushort_t*)obuf;              // dead before attn writes obuf
  ushort_t* ql  = qh + 4194304;
  ushort_t* vh  = ql + 4194304;
  ushort_t* ctx = (ushort_t*)qf;                // qf last read in attn; ctx written after

  pack2_kernel<<<4096, 256, 0, stream>>>(query, qh, ql);
  pack1_kernel<<<4096, 256, 0, stream>>>(value, vh);
  packT_kernel<<<dim3(16, 16), 256, 0, stream>>>(Wq, WqTh, WqTl, 1024, 1024);
  packT_kernel<<<dim3(16, 16), 256, 0, stream>>>(Wv, WvTh, (ushort_t*)nullptr, 1024, 1024);
  packT_kernel<<<dim3(16, 16), 256, 0, stream>>>(Wo, WoTh, (ushort_t*)nullptr, 1024, 1024);
  gemm_mfma<<<dim3(16, 32), 256, 0, stream>>>(qh, ql, WqTh, WqTl, bq, qf, 4096, 1024, 1024);
  gemm_mfma<<<dim3(16, 32), 256, 0, stream>>>(vh, (ushort_t*)nullptr, WvTh, (ushort_t*)nullptr, bv, vf, 4096, 1024, 1024);
  norm_kernel<<<4096, 256, 0, stream>>>(qf, inv_nrm);
  hash_kernel<<<256, 256, 0, stream>>>(qf, hw, hashb);
  sort_kernel<<<32, 256, 0, stream>>>(hashb, pperm, pinv);
  attn_kernel<<<dim3(64, 8, 4), 256, 0, stream>>>(qf, vf, inv_nrm, hashb, pperm, pinv, obuf, zbuf);
  combine_kernel<<<16384, 256, 0, stream>>>(obuf, zbuf, ctx);
  gemm_mfma<<<dim3(16, 32), 256, 0, stream>>>(ctx, (ushort_t*)nullptr, WoTh, (ushort_t*)nullptr, bo, (float*)d_out, 4096, 1024, 1024);
}

// Round 4
// 272.328 us; speedup vs baseline: 1.8517x; 1.0396x over previous
//
#include <hip/hip_runtime.h>

typedef unsigned short ushort_t;
typedef __bf16 bf16x8 __attribute__((ext_vector_type(8)));
typedef float f32x4 __attribute__((ext_vector_type(4)));

#define T_DIM 2048
#define B_DIM 2
#define E_DIM 1024
#define H_DIM 8
#define R_DIM 2
#define D_DIM 128
#define M_WIN 96
#define SCALING 0.08838834764831845f   // D^-0.5
#define LN2F 0.69314718055994530942f

__device__ __forceinline__ float bfu(unsigned u) {
  union { unsigned i; float f; } x; x.i = u << 16; return x.f;
}
__device__ __forceinline__ unsigned f2bf(float f) {
  union { float f; unsigned i; } x; x.f = f;
  unsigned r = x.i + 0x7fffu + ((x.i >> 16) & 1u);
  return r >> 16;
}
__device__ __forceinline__ void gl_lds16(const void* g, void* l) {
  __builtin_amdgcn_global_load_lds(
      (const __attribute__((address_space(1))) unsigned int*)g,
      (__attribute__((address_space(3))) unsigned int*)l, 16, 0, 0);
}

// ---------------------------------------------------------------------------
// packA: query+value fp32 -> bf16 in one launch (blockIdx selects tensor).
// ---------------------------------------------------------------------------
__global__ __launch_bounds__(256) void packA_kernel(const float* __restrict__ q,
                                                    const float* __restrict__ v,
                                                    ushort_t* __restrict__ qh,
                                                    ushort_t* __restrict__ vh)
{
  int bid = blockIdx.x;
  const float* src = (bid < 4096) ? q : v;
  ushort_t* dst = (bid < 4096) ? qh : vh;
  int i = ((bid & 4095) * 256 + threadIdx.x) * 4;
  float4 x = *(const float4*)&src[i];
  uint2 oh;
  oh.x = f2bf(x.x) | (f2bf(x.y) << 16);
  oh.y = f2bf(x.z) | (f2bf(x.w) << 16);
  *(uint2*)&dst[i] = oh;
}

// ---------------------------------------------------------------------------
// packT: W[K][N] fp32 -> WT[N][K] bf16. z selects {Wq,Wv,Wo}.
// ---------------------------------------------------------------------------
__global__ __launch_bounds__(256) void packT_kernel(
    const float* __restrict__ w0, const float* __restrict__ w1,
    const float* __restrict__ w2, ushort_t* __restrict__ o0,
    ushort_t* __restrict__ o1, ushort_t* __restrict__ o2)
{
  const float* in = (blockIdx.z == 0) ? w0 : (blockIdx.z == 1) ? w1 : w2;
  ushort_t* hi = (blockIdx.z == 0) ? o0 : (blockIdx.z == 1) ? o1 : o2;
  __shared__ float tile[64][65];
  const int tid = threadIdx.x;
  const int k0 = blockIdx.y * 64, n0 = blockIdx.x * 64;
  const int tr = tid >> 4, tc4 = (tid & 15) * 4;
#pragma unroll
  for (int rr = 0; rr < 64; rr += 16)
    *(float4*)&tile[tr + rr][tc4] = *(const float4*)&in[(size_t)(k0 + tr + rr) * E_DIM + n0 + tc4];
  __syncthreads();
#pragma unroll
  for (int rr = 0; rr < 64; rr += 16) {
    int n = n0 + tr + rr;
    uint2 oh;
    oh.x = f2bf(tile[tc4 + 0][tr + rr]) | (f2bf(tile[tc4 + 1][tr + rr]) << 16);
    oh.y = f2bf(tile[tc4 + 2][tr + rr]) | (f2bf(tile[tc4 + 3][tr + rr]) << 16);
    *(uint2*)&hi[(size_t)n * E_DIM + k0 + tc4] = oh;
  }
}

// ---------------------------------------------------------------------------
// fuseF: F[e][rh*4+n] = sum_d Wq[e][h*128+d]*hw[r][h][d][n]; c = bq-projection.
// Hash is scale-invariant and linear => hash(query@Wq+bq) == argmax(query@F+c).
// One block per (r,h).
// ---------------------------------------------------------------------------
__global__ __launch_bounds__(256) void fuseF_kernel(const float* __restrict__ Wq,
                                                    const float* __restrict__ bq,
                                                    const float* __restrict__ hw,
                                                    float* __restrict__ F,
                                                    float* __restrict__ cvec)
{
  __shared__ float wl[512];   // [d][n]
  const int rh = blockIdx.x, h = rh & 7;
  const int tid = threadIdx.x;
  for (int i = tid; i < 512; i += 256) wl[i] = hw[rh * 512 + i];
  __syncthreads();
  for (int e = tid; e < E_DIM; e += 256) {
    const float* wr = Wq + (size_t)e * E_DIM + h * D_DIM;
    float a0 = 0.f, a1 = 0.f, a2 = 0.f, a3 = 0.f;
    for (int d = 0; d < 128; d += 4) {
      float4 q4 = *(const float4*)&wr[d];
      float4 w0 = *(const float4*)&wl[d * 4];
      float4 w1 = *(const float4*)&wl[d * 4 + 4];
      float4 w2 = *(const float4*)&wl[d * 4 + 8];
      float4 w3 = *(const float4*)&wl[d * 4 + 12];
      a0 += q4.x * w0.x + q4.y * w1.x + q4.z * w2.x + q4.w * w3.x;
      a1 += q4.x * w0.y + q4.y * w1.y + q4.z * w2.y + q4.w * w3.y;
      a2 += q4.x * w0.z + q4.y * w1.z + q4.z * w2.z + q4.w * w3.z;
      a3 += q4.x * w0.w + q4.y * w1.w + q4.z * w2.w + q4.w * w3.w;
    }
    float4 o; o.x = a0; o.y = a1; o.z = a2; o.w = a3;
    *(float4*)&F[(size_t)e * 64 + rh * 4] = o;
  }
  if (tid < 4) {
    float acc = 0.f;
    for (int d = 0; d < 128; ++d) acc += bq[h * D_DIM + d] * wl[d * 4 + tid];
    cvec[rh * 4 + tid] = acc;
  }
}

// ---------------------------------------------------------------------------
// hashlin: lin[row][64] = query@F + c (fp32), fused argmax over [lin,-lin]
// per (r,h) -> hashb. Block = 16 rows; thread (ty=row, tx=rh).
// ---------------------------------------------------------------------------
__global__ __launch_bounds__(256) void hashlin_kernel(const float* __restrict__ query,
                                                      const float* __restrict__ F,
                                                      const float* __restrict__ cvec,
                                                      int* __restrict__ hashb)
{
  __shared__ float As[32][17];
  __shared__ float Fs[32][64];
  const int tid = threadIdx.x;
  const int ty = tid >> 4, tx = tid & 15;
  const int r0 = blockIdx.x * 16;
  float acc0 = 0.f, acc1 = 0.f, acc2 = 0.f, acc3 = 0.f;
  for (int k0 = 0; k0 < E_DIM; k0 += 32) {
    __syncthreads();
    {
      int i = tid * 2, row = i >> 5, kk = i & 31;
      float2 a2 = *(const float2*)&query[(size_t)(r0 + row) * E_DIM + k0 + kk];
      As[kk][row] = a2.x; As[kk + 1][row] = a2.y;
    }
    {
      int i = tid * 8, kk = i >> 6, cc = i & 63;
      float4 f0 = *(const float4*)&F[(size_t)(k0 + kk) * 64 + cc];
      float4 f1 = *(const float4*)&F[(size_t)(k0 + kk) * 64 + cc + 4];
      *(float4*)&Fs[kk][cc] = f0;
      *(float4*)&Fs[kk][cc + 4] = f1;
    }
    __syncthreads();
#pragma unroll
    for (int kk = 0; kk < 32; ++kk) {
      float a = As[kk][ty];
      float4 f4 = *(const float4*)&Fs[kk][tx * 4];
      acc0 += a * f4.x; acc1 += a * f4.y; acc2 += a * f4.z; acc3 += a * f4.w;
    }
  }
  float4 c4 = *(const float4*)&cvec[tx * 4];
  float lin[4] = {acc0 + c4.x, acc1 + c4.y, acc2 + c4.z, acc3 + c4.w};
  float best = lin[0]; int bi = 0;
#pragma unroll
  for (int idx = 1; idx < 8; ++idx) {
    float v = (idx < 4) ? lin[idx] : -lin[idx - 4];
    if (v > best) { best = v; bi = idx; }   // first-occurrence argmax
  }
  int grow = r0 + ty;             // t*B + b
  int t = grow >> 1, b = grow & 1;
  int rr = tx >> 3, hh = tx & 7;
  hashb[(size_t)((b * R_DIM + rr) * H_DIM + hh) * T_DIM + t] = bi;
}

// ---------------------------------------------------------------------------
// MFMA GEMM 4096x1024x1024, tile 128x64, BK=32, global_load_lds(16B).
// z selects problem {0,1}. C fp32 = A@B + bias.
// ---------------------------------------------------------------------------
__global__ __launch_bounds__(256) void gemm_mfma(
    const ushort_t* __restrict__ A0, const ushort_t* __restrict__ B0,
    const float* __restrict__ bias0, float* __restrict__ C0,
    const ushort_t* __restrict__ A1, const ushort_t* __restrict__ B1,
    const float* __restrict__ bias1, float* __restrict__ C1)
{
  const ushort_t* Ah = blockIdx.z ? A1 : A0;
  const ushort_t* Bh = blockIdx.z ? B1 : B0;
  const float* bias = blockIdx.z ? bias1 : bias0;
  float* C = blockIdx.z ? C1 : C0;

  __shared__ ushort_t As[128 * 32];
  __shared__ ushort_t Bs[64 * 32];
  const int tid = threadIdx.x;
  const int w = tid >> 6, lane = tid & 63;
  const int lm = lane & 15, quad = lane >> 4;
  const int wr = w >> 1, wc = w & 1;
  const int m0 = blockIdx.y * 128, n0 = blockIdx.x * 64;

  f32x4 acc[4][2] = {};

  for (int k0 = 0; k0 < E_DIM; k0 += 32) {
    __syncthreads();
#pragma unroll
    for (int j = 0; j < 2; ++j) {
      int g = j * 256 + w * 64 + lane;
      gl_lds16(Ah + (size_t)(m0 + (g >> 2)) * E_DIM + k0 + (g & 3) * 8,
               &As[(size_t)(j * 256 + w * 64) * 8]);
    }
    {
      int g = w * 64 + lane;
      gl_lds16(Bh + (size_t)(n0 + (g >> 2)) * E_DIM + k0 + (g & 3) * 8,
               &Bs[(size_t)(w * 64) * 8]);
    }
    __syncthreads();

    bf16x8 av[4], bv[2];
#pragma unroll
    for (int i = 0; i < 4; ++i) av[i] = *(const bf16x8*)&As[(wr * 64 + i * 16 + lm) * 32 + quad * 8];
#pragma unroll
    for (int j = 0; j < 2; ++j) bv[j] = *(const bf16x8*)&Bs[(wc * 32 + j * 16 + lm) * 32 + quad * 8];
#pragma unroll
    for (int i = 0; i < 4; ++i)
#pragma unroll
      for (int j = 0; j < 2; ++j)
        acc[i][j] = __builtin_amdgcn_mfma_f32_16x16x32_bf16(av[i], bv[j], acc[i][j], 0, 0, 0);
  }

#pragma unroll
  for (int j = 0; j < 2; ++j) {
    int col = n0 + wc * 32 + j * 16 + lm;
    float bj = bias[col];
#pragma unroll
    for (int i = 0; i < 4; ++i)
#pragma unroll
      for (int rg = 0; rg < 4; ++rg)
        C[(size_t)(m0 + wr * 64 + i * 16 + quad * 4 + rg) * E_DIM + col] = acc[i][j][rg] + bj;
  }
}

// ---------------------------------------------------------------------------
// inv_norm[row] = 1/||qf[row,:]||
// ---------------------------------------------------------------------------
__global__ __launch_bounds__(256) void norm_kernel(const float* __restrict__ qf,
                                                   float* __restrict__ inv_nrm)
{
  int row = blockIdx.x, tid = threadIdx.x;
  const float* r = qf + (size_t)row * E_DIM;
  float4 v = *(const float4*)(r + tid * 4);
  float s = v.x * v.x + v.y * v.y + v.z * v.z + v.w * v.w;
  for (int off = 1; off < 64; off <<= 1) s += __shfl_xor(s, off);
  __shared__ float part[4];
  if ((tid & 63) == 0) part[tid >> 6] = s;
  __syncthreads();
  if (tid == 0) {
    float t = part[0] + part[1] + part[2] + part[3];
    inv_nrm[row] = 1.0f / sqrtf(t);
  }
}

// ---------------------------------------------------------------------------
// Stable counting sort by hash in [0,8) per (b,r,h). Parallel scan.
// ---------------------------------------------------------------------------
__global__ __launch_bounds__(256) void sort_kernel(const int* __restrict__ hashb,
                                                   int* __restrict__ p, int* __restrict__ inv)
{
  const int bid = blockIdx.x, tid = threadIdx.x;
  const int lane = tid & 63, w = tid >> 6;
  const int* hrow = hashb + (size_t)bid * T_DIM;
  __shared__ int mat[8][256];
  __shared__ int btot[8], bbase[8];
  int cnt[8];
#pragma unroll
  for (int v = 0; v < 8; ++v) cnt[v] = 0;
  int hv[8];
#pragma unroll
  for (int j = 0; j < 8; ++j) { hv[j] = hrow[tid * 8 + j]; cnt[hv[j]]++; }
#pragma unroll
  for (int v = 0; v < 8; ++v) mat[v][tid] = cnt[v];
  __syncthreads();
  for (int v = w; v < 8; v += 4) {
    int4 c4 = *(const int4*)&mat[v][lane * 4];
    int s = c4.x + c4.y + c4.z + c4.w;
    int x = s;
    for (int off = 1; off < 64; off <<= 1) {
      int y = __shfl_up(x, off);
      if (lane >= off) x += y;
    }
    int excl = x - s;
    mat[v][lane * 4 + 0] = excl;
    mat[v][lane * 4 + 1] = excl + c4.x;
    mat[v][lane * 4 + 2] = excl + c4.x + c4.y;
    mat[v][lane * 4 + 3] = excl + c4.x + c4.y + c4.z;
    if (lane == 63) btot[v] = x;
  }
  __syncthreads();
  if (tid == 0) {
    int run = 0;
    for (int v = 0; v < 8; ++v) { bbase[v] = run; run += btot[v]; }
  }
  __syncthreads();
#pragma unroll
  for (int v = 0; v < 8; ++v) cnt[v] = 0;
#pragma unroll
  for (int j = 0; j < 8; ++j) {
    int v = hv[j];
    int pos = bbase[v] + mat[v][tid] + cnt[v];
    cnt[v]++;
    p[(size_t)bid * T_DIM + pos] = tid * 8 + j;
    inv[(size_t)bid * T_DIM + tid * 8 + j] = pos;
  }
}

// ---------------------------------------------------------------------------
// Chunked LSH attention, MFMA. Block per (c,h,b*2+r), 256 threads.
// Meta packed (t | hash<<11 | chunk_other<<14) to fit LDS <= 40KB (4 blk/CU).
// P overlaid in-place into SS rows (row-local => race-free, 16B aligned).
// o written bf16.
// ---------------------------------------------------------------------------
__global__ __launch_bounds__(256) void attn_kernel(
    const float* __restrict__ qf, const float* __restrict__ vf,
    const float* __restrict__ inv_nrm, const int* __restrict__ hashb,
    const int* __restrict__ p, const int* __restrict__ inv,
    ushort_t* __restrict__ o_out, float* __restrict__ z_out)
{
  const int c = blockIdx.x, h = blockIdx.y, bz = blockIdx.z;
  const int b = bz >> 1, r = bz & 1;
  const int brh = (b * R_DIM + r) * H_DIM + h;
  const int brh_o = (b * R_DIM + (r ^ 1)) * H_DIM + h;
  const int tid = threadIdx.x;
  const int lane = tid & 63, w = tid >> 6;
  const int lm = lane & 15, quad = lane >> 4;

  // phase1: {Qs[32][136]@0, Ks[96][136]@8704}  (34816 B)
  // phase2: {VT[128][104]@0, SS[32][100]f32@26624 with P[32][200]bf16 in-row}
  __shared__ __align__(16) unsigned char smem[39424];
  ushort_t* Qs = (ushort_t*)smem;
  ushort_t* Ks = (ushort_t*)(smem + 8704);
  ushort_t* VT = (ushort_t*)smem;
  float*    SS = (float*)(smem + 26624);
  ushort_t* Ps = (ushort_t*)(smem + 26624);
  __shared__ int skp[M_WIN], sqp[32];
  __shared__ float s_invn[M_WIN];

  if (tid < M_WIN) {
    int m = tid;
    int chunk = (c + (m >> 5) + 63) & 63;          // c-1, c, c+1 (wrap)
    int pos = chunk * 32 + (m & 31);
    int t = p[(size_t)brh * T_DIM + pos];
    int hh = hashb[(size_t)brh * T_DIM + t];
    int co = inv[(size_t)brh_o * T_DIM + t] >> 5;
    skp[m] = t | (hh << 11) | (co << 14);
    s_invn[m] = inv_nrm[t * B_DIM + b];
    if (m < 32) {
      int tq = p[(size_t)brh * T_DIM + c * 32 + m];
      int qh = hashb[(size_t)brh * T_DIM + tq];
      int qco = inv[(size_t)brh_o * T_DIM + tq] >> 5;
      sqp[m] = tq | (qh << 11) | (qco << 14);
    }
  }
  __syncthreads();

  // stage Q (scaled) and K (normalized) as bf16
  for (int idx = tid; idx < 1024; idx += 256) {
    int row = idx >> 5, seg = idx & 31;
    int t = sqp[row] & 2047;
    float4 v = *(const float4*)(qf + ((size_t)(t * B_DIM + b) << 10) + h * D_DIM + seg * 4);
    uint2 o2;
    o2.x = f2bf(v.x * SCALING) | (f2bf(v.y * SCALING) << 16);
    o2.y = f2bf(v.z * SCALING) | (f2bf(v.w * SCALING) << 16);
    *(uint2*)&Qs[row * 136 + seg * 4] = o2;
  }
  for (int idx = tid; idx < 3072; idx += 256) {
    int m = idx >> 5, seg = idx & 31;
    int t = skp[m] & 2047;
    float inrm = s_invn[m];
    float4 v = *(const float4*)(qf + ((size_t)(t * B_DIM + b) << 10) + h * D_DIM + seg * 4);
    uint2 o2;
    o2.x = f2bf(v.x * inrm) | (f2bf(v.y * inrm) << 16);
    o2.y = f2bf(v.z * inrm) | (f2bf(v.w * inrm) << 16);
    *(uint2*)&Ks[m * 136 + seg * 4] = o2;
  }
  __syncthreads();

  // scores MFMA: wave w -> m-tile (w&1), n-tiles (w>>1)*3 + {0,1,2}
  const int mw = w & 1, nset = w >> 1;
  bf16x8 av[4];
#pragma unroll
  for (int kk = 0; kk < 4; ++kk)
    av[kk] = *(const bf16x8*)&Qs[(mw * 16 + lm) * 136 + kk * 32 + quad * 8];
  f32x4 sacc[3] = {};
#pragma unroll
  for (int jj = 0; jj < 3; ++jj) {
    int nt = nset * 3 + jj;
#pragma unroll
    for (int kk = 0; kk < 4; ++kk) {
      bf16x8 bv = *(const bf16x8*)&Ks[(nt * 16 + lm) * 136 + kk * 32 + quad * 8];
      sacc[jj] = __builtin_amdgcn_mfma_f32_16x16x32_bf16(av[kk], bv, sacc[jj], 0, 0, 0);
    }
  }
  __syncthreads();   // Q/K reads done; safe to overwrite union

  // epilogue: masks -> SS (C layout: row = mw*16+quad*4+rg, col = nt*16+lm)
  const int rowb = mw * 16 + quad * 4;
#pragma unroll
  for (int jj = 0; jj < 3; ++jj) {
    int col = (nset * 3 + jj) * 16 + lm;
    int kp = skp[col];
#pragma unroll
    for (int rg = 0; rg < 4; ++rg) {
      int qp = sqp[rowb + rg];
      float sc = sacc[jj][rg];
      if ((kp ^ qp) & 0x3800) sc -= 1.0e16f;       // mask_different_hashes
      if (!((kp ^ qp) & 0x7FF)) sc -= 1.0e8f;      // mask_current
      int dc = ((kp >> 14) - (qp >> 14)) & 63;
      if (dc <= 1 || dc == 63) sc -= LN2F;         // -log(dup)
      SS[(rowb + rg) * 100 + col] = sc;
    }
  }
  // stage V^T: VT[d][m] = V[m][d]
  for (int idx = tid; idx < 3072; idx += 256) {
    int d = idx & 127, mg = idx >> 7;   // mg in [0,24)
    int t0 = skp[mg * 4 + 0] & 2047, t1 = skp[mg * 4 + 1] & 2047;
    int t2 = skp[mg * 4 + 2] & 2047, t3 = skp[mg * 4 + 3] & 2047;
    const size_t off = (size_t)h * D_DIM + d;
    unsigned vv0 = f2bf(vf[((size_t)(t0 * B_DIM + b) << 10) + off]);
    unsigned vv1 = f2bf(vf[((size_t)(t1 * B_DIM + b) << 10) + off]);
    unsigned vv2 = f2bf(vf[((size_t)(t2 * B_DIM + b) << 10) + off]);
    unsigned vv3 = f2bf(vf[((size_t)(t3 * B_DIM + b) << 10) + off]);
    uint2 o2; o2.x = vv0 | (vv1 << 16); o2.y = vv2 | (vv3 << 16);
    *(uint2*)&VT[d * 104 + mg * 4] = o2;
  }
  __syncthreads();

  // softmax over 96 cols: 8 threads per row; P written in-place in SS row
  {
    const int l = tid >> 3, g = tid & 7;
    float smy[12];
#pragma unroll
    for (int j = 0; j < 12; ++j) smy[j] = SS[l * 100 + g + 8 * j];
    float mx = smy[0];
#pragma unroll
    for (int j = 1; j < 12; ++j) mx = fmaxf(mx, smy[j]);
    mx = fmaxf(mx, __shfl_xor(mx, 1));
    mx = fmaxf(mx, __shfl_xor(mx, 2));
    mx = fmaxf(mx, __shfl_xor(mx, 4));
    float sum = 0.f, ey[12];
#pragma unroll
    for (int j = 0; j < 12; ++j) { ey[j] = expf(smy[j] - mx); sum += ey[j]; }
    sum += __shfl_xor(sum, 1);
    sum += __shfl_xor(sum, 2);
    sum += __shfl_xor(sum, 4);
    float inv_s = 1.0f / sum;
#pragma unroll
    for (int j = 0; j < 12; ++j)
      Ps[l * 200 + g + 8 * j] = (ushort_t)f2bf(ey[j] * inv_s);
    if (g == 0) z_out[(size_t)brh * T_DIM + (sqp[l] & 2047)] = mx + logf(sum);
  }
  __syncthreads();

  // PV MFMA: wave w -> m-tile (w&1), d-tiles (w>>1)*4 + {0..3}; K=96
  const int dset = w >> 1;
  bf16x8 pa[3];
#pragma unroll
  for (int kk = 0; kk < 3; ++kk)
    pa[kk] = *(const bf16x8*)&Ps[(mw * 16 + lm) * 200 + kk * 32 + quad * 8];
  f32x4 oacc[4] = {};
#pragma unroll
  for (int jj = 0; jj < 4; ++jj) {
    int dt = dset * 4 + jj;
#pragma unroll
    for (int kk = 0; kk < 3; ++kk) {
      bf16x8 bv = *(const bf16x8*)&VT[(dt * 16 + lm) * 104 + kk * 32 + quad * 8];
      oacc[jj] = __builtin_amdgcn_mfma_f32_16x16x32_bf16(pa[kk], bv, oacc[jj], 0, 0, 0);
    }
  }
#pragma unroll
  for (int jj = 0; jj < 4; ++jj) {
    int col = (dset * 4 + jj) * 16 + lm;
#pragma unroll
    for (int rg = 0; rg < 4; ++rg) {
      int tqo = sqp[rowb + rg] & 2047;
      o_out[((size_t)brh * T_DIM + tqo) * D_DIM + col] = (ushort_t)f2bf(oacc[jj][rg]);
    }
  }
}

// ---------------------------------------------------------------------------
// Combine rounds (bf16 o) -> ctx bf16. 4 d per thread.
// ---------------------------------------------------------------------------
__global__ __launch_bounds__(256) void combine_kernel(const ushort_t* __restrict__ obf,
                                                      const float* __restrict__ z_buf,
                                                      ushort_t* __restrict__ ctx)
{
  int gid = blockIdx.x * 256 + threadIdx.x;   // [0, 1048576)
  int d4 = gid & 31;
  int t = (gid >> 5) & (T_DIM - 1);
  int h = (gid >> 16) & 7;
  int b = gid >> 19;
  int brh0 = (b * R_DIM + 0) * H_DIM + h;
  int brh1 = brh0 + H_DIM;
  float z0 = z_buf[(size_t)brh0 * T_DIM + t], z1 = z_buf[(size_t)brh1 * T_DIM + t];
  float mz = fmaxf(z0, z1);
  float e0 = expf(z0 - mz), e1 = expf(z1 - mz);
  float is = 1.0f / (e0 + e1);
  float w0 = e0 * is, w1 = e1 * is;
  uint2 a = *(const uint2*)&obf[((size_t)brh0 * T_DIM + t) * D_DIM + d4 * 4];
  uint2 cc = *(const uint2*)&obf[((size_t)brh1 * T_DIM + t) * D_DIM + d4 * 4];
  uint2 o;
  o.x = f2bf(w0 * bfu(a.x & 0xffffu) + w1 * bfu(cc.x & 0xffffu)) |
        (f2bf(w0 * bfu(a.x >> 16) + w1 * bfu(cc.x >> 16)) << 16);
  o.y = f2bf(w0 * bfu(a.y & 0xffffu) + w1 * bfu(cc.y & 0xffffu)) |
        (f2bf(w0 * bfu(a.y >> 16) + w1 * bfu(cc.y >> 16)) << 16);
  *(uint2*)&ctx[((size_t)(t * B_DIM + b) << 10) + h * D_DIM + d4 * 4] = o;
}

// ---------------------------------------------------------------------------
extern "C" void kernel_launch(void* const* d_in, const int* in_sizes, int n_in,
                              void* d_out, int out_size, void* d_ws, size_t ws_size,
                              hipStream_t stream)
{
  const float* query = (const float*)d_in[0];
  // d_in[1] = key, unused (share_kq)
  const float* value = (const float*)d_in[2];
  const float* Wq = (const float*)d_in[3];
  const float* bq = (const float*)d_in[4];
  const float* Wv = (const float*)d_in[5];
  const float* bv = (const float*)d_in[6];
  const float* Wo = (const float*)d_in[7];
  const float* bo = (const float*)d_in[8];
  const float* hw = (const float*)d_in[9];

  float* ws = (float*)d_ws;
  float* qf   = ws;                             // 4,194,304 f
  float* vf   = qf + 4194304;                   // 4,194,304 f
  float* bigf = vf + 4194304;                   // 6,291,456 f region
  ushort_t* obuf = (ushort_t*)bigf;             // 8,388,608 us (16.8 MB)
  ushort_t* ctx  = obuf + 8388608;              // 4,194,304 us
  ushort_t* qh   = (ushort_t*)bigf;             // overlay: dead before attn
  ushort_t* vh   = qh + 4194304;                //   (qh+vh == obuf extent)
  ushort_t* WqTh = (ushort_t*)(bigf + 6291456); // 1,048,576 us each
  ushort_t* WvTh = WqTh + 1048576;
  ushort_t* WoTh = WvTh + 1048576;
  float* F       = (float*)(WoTh + 1048576);    // 65,536 f
  float* cvec    = F + 65536;                   // 64 f
  float* zbuf    = cvec + 64;                   // 65,536 f
  float* inv_nrm = zbuf + 65536;                // 4,096 f
  int*   hashb   = (int*)(inv_nrm + 4096);      // 65,536 i
  int*   pperm   = hashb + 65536;
  int*   pinv    = pperm + 65536;

  packA_kernel<<<8192, 256, 0, stream>>>(query, value, qh, vh);
  packT_kernel<<<dim3(16, 16, 3), 256, 0, stream>>>(Wq, Wv, Wo, WqTh, WvTh, WoTh);
  fuseF_kernel<<<16, 256, 0, stream>>>(Wq, bq, hw, F, cvec);
  hashlin_kernel<<<256, 256, 0, stream>>>(query, F, cvec, hashb);
  gemm_mfma<<<dim3(16, 32, 2), 256, 0, stream>>>(qh, WqTh, bq, qf, vh, WvTh, bv, vf);
  norm_kernel<<<4096, 256, 0, stream>>>(qf, inv_nrm);
  sort_kernel<<<32, 256, 0, stream>>>(hashb, pperm, pinv);
  attn_kernel<<<dim3(64, 8, 4), 256, 0, stream>>>(qf, vf, inv_nrm, hashb, pperm, pinv, obuf, zbuf);
  combine_kernel<<<4096, 256, 0, stream>>>(obuf, zbuf, ctx);
  gemm_mfma<<<dim3(16, 32, 1), 256, 0, stream>>>(ctx, WoTh, bo, (float*)d_out,
                                                 (ushort_t*)nullptr, (ushort_t*)nullptr,
                                                 (const float*)nullptr, (float*)nullptr);
}